// Round 1
// baseline (220.511 us; speedup 1.0000x reference)
//
#include <hip/hip_runtime.h>
#include <cstdint>

#define Bq 16
#define Nq 512
#define Dq 12
#define HID 32
#define HEADS 4
#define Cq 8

// ws layout (float offsets)
#define OFF_G     0u        // [b][n][32]         262144 floats
#define OFF_AS    262144u   // [b][n][4]           32768
#define OFF_AD    294912u   // [b][n][4]           32768
#define OFF_LSUM  327680u   // [b][h][j]           32768  (atomic, zeroed)
#define OFF_ACC   360448u   // [b][h][c][j]       262144  (atomic, zeroed)
#define OFF_TI    622592u   // [b][n][32]         262144
#define OFF_TJB   884736u   // [b][h][j]          262144
#define OFF_PACK  1146880u  // uint64 [b][i][j/64] 65536 u64 (as float offset)
// total bytes: (1146880 + 131072) * 4 = 5,111,808

__global__ void k0_node(const float* __restrict__ x, const float* __restrict__ Wp,
                        const float* __restrict__ bp, const float* __restrict__ Wg,
                        const float* __restrict__ att_src, const float* __restrict__ att_dst,
                        float* __restrict__ ws) {
    int nid = blockIdx.x * blockDim.x + threadIdx.x;
    if (nid >= Bq * Nq) return;
    float xv[Dq];
#pragma unroll
    for (int d = 0; d < Dq; d++) xv[d] = x[nid * Dq + d];
    float h[HID];
#pragma unroll
    for (int k = 0; k < HID; k++) {
        float s = bp[k];
#pragma unroll
        for (int d = 0; d < Dq; d++) s = fmaf(Wp[k * Dq + d], xv[d], s);
        h[k] = s > 0.f ? s : 0.f;
    }
    float g[HID];
#pragma unroll
    for (int k = 0; k < HID; k++) {
        float s = 0.f;
#pragma unroll
        for (int d = 0; d < HID; d++) s = fmaf(Wg[k * HID + d], h[d], s);
        g[k] = s;
    }
    float* gout = ws + OFF_G + (size_t)nid * HID;
#pragma unroll
    for (int k = 0; k < HID; k++) gout[k] = g[k];
#pragma unroll
    for (int hh = 0; hh < HEADS; hh++) {
        float ss = 0.f, sd = 0.f;
#pragma unroll
        for (int c = 0; c < Cq; c++) {
            ss = fmaf(g[hh * Cq + c], att_src[hh * Cq + c], ss);
            sd = fmaf(g[hh * Cq + c], att_dst[hh * Cq + c], sd);
        }
        ws[OFF_AS + nid * HEADS + hh] = ss;
        ws[OFF_AD + nid * HEADS + hh] = sd;
    }
}

// grid (ichunk=8, jtile=2, b=16), block 256. Thread owns j, loops 64 i's.
__global__ void __launch_bounds__(256) k1_aggregate(const int* __restrict__ adj,
                                                    float* __restrict__ ws) {
    int b = blockIdx.z;
    int j = blockIdx.y * 256 + threadIdx.x;
    int i0 = blockIdx.x * 64;
    const float* as_w = ws + OFF_AS;
    const float* ad_w = ws + OFF_AD;
    const float* g_w = ws + OFF_G;
    uint64_t* packed = (uint64_t*)(ws + OFF_PACK);

    float adv[HEADS];
#pragma unroll
    for (int h = 0; h < HEADS; h++) adv[h] = ad_w[(b * Nq + j) * HEADS + h];
    float lsum[HEADS] = {0.f, 0.f, 0.f, 0.f};
    float acc[HEADS][Cq] = {};

    for (int ii = 0; ii < 64; ii++) {
        int i = i0 + ii;
        int av = adj[((size_t)b * Nq + i) * Nq + j];
        unsigned long long m = __ballot(av != 0);
        if ((threadIdx.x & 63) == 0)
            packed[((size_t)b * Nq + i) * (Nq / 64) + (j >> 6)] = m;
        bool msk = (av != 0) || (i == j);
        const float* gi = g_w + ((size_t)b * Nq + i) * HID;   // wave-uniform addr
        const float* asi = as_w + ((size_t)b * Nq + i) * HEADS;
#pragma unroll
        for (int h = 0; h < HEADS; h++) {
            float z = asi[h] + adv[h];
            float lk = z > 0.f ? z : 0.2f * z;
            float e = msk ? __expf(lk) : 0.f;   // no max-shift: |z|<~2, exact enough
            lsum[h] += e;
#pragma unroll
            for (int c = 0; c < Cq; c++) acc[h][c] = fmaf(e, gi[h * Cq + c], acc[h][c]);
        }
    }
    float* lsw = ws + OFF_LSUM;
    float* accw = ws + OFF_ACC;
#pragma unroll
    for (int h = 0; h < HEADS; h++) {
        atomicAdd(&lsw[(b * HEADS + h) * Nq + j], lsum[h]);
#pragma unroll
        for (int c = 0; c < Cq; c++)
            atomicAdd(&accw[((b * HEADS + h) * Cq + c) * Nq + j], acc[h][c]);
    }
}

__global__ void k2_finalize(const float* __restrict__ bias_g, const float* __restrict__ W1,
                            const float* __restrict__ b1, float* __restrict__ ws) {
    int nid = blockIdx.x * blockDim.x + threadIdx.x;
    if (nid >= Bq * Nq) return;
    int b = nid >> 9, j = nid & (Nq - 1);
    float hg[HID];
#pragma unroll
    for (int h = 0; h < HEADS; h++) {
        float inv = 1.f / ws[OFF_LSUM + (b * HEADS + h) * Nq + j];
#pragma unroll
        for (int c = 0; c < Cq; c++)
            hg[h * Cq + c] = ws[OFF_ACC + ((b * HEADS + h) * Cq + c) * Nq + j] * inv
                             + bias_g[h * Cq + c];
    }
#pragma unroll
    for (int h = 0; h < HID; h++) {
        float si = 0.f, sj = 0.f;
#pragma unroll
        for (int d = 0; d < HID; d++) {
            si = fmaf(hg[d], W1[h * 2 * HID + d], si);
            sj = fmaf(hg[d], W1[h * 2 * HID + HID + d], sj);
        }
        ws[OFF_TI + (size_t)nid * HID + h] = si;
        ws[OFF_TJB + (b * HID + h) * Nq + j] = sj + b1[h];  // fold b1 here
    }
}

// grid (N/16=32 i-tiles, b=16), block 512: thread owns j, tjb[32] in VGPRs.
__global__ void __launch_bounds__(512) k3_score(const float* __restrict__ w2_p,
                                                const float* __restrict__ b2_p,
                                                const float* __restrict__ ws,
                                                float* __restrict__ out) {
    int b = blockIdx.y;
    int i0 = blockIdx.x * 16;
    int j = threadIdx.x;
    float tjb[HID];
#pragma unroll
    for (int h = 0; h < HID; h++) tjb[h] = ws[OFF_TJB + (b * HID + h) * Nq + j];
    float w2l[HID];
#pragma unroll
    for (int h = 0; h < HID; h++) w2l[h] = w2_p[h];   // uniform -> SGPRs
    float b2 = b2_p[0];
    const uint64_t* packed = (const uint64_t*)(ws + OFF_PACK);
    const float* tiw = ws + OFF_TI;
    for (int ii = 0; ii < 16; ii++) {
        int i = i0 + ii;
        uint64_t m = packed[((size_t)b * Nq + i) * (Nq / 64) + (j >> 6)];
        bool on = (((m >> (j & 63)) & 1ull) != 0) && (i != j);
        const float* ti = tiw + ((size_t)b * Nq + i) * HID;  // wave-uniform
        float s = b2;
#pragma unroll
        for (int h = 0; h < HID; h++) {
            float t = ti[h] + tjb[h];
            t = t > 0.f ? t : 0.f;
            s = fmaf(t, w2l[h], s);
        }
        float score = 1.f / (1.f + __expf(-s));
        out[((size_t)b * Nq + i) * Nq + j] = on ? score : 0.f;
    }
}

extern "C" void kernel_launch(void* const* d_in, const int* in_sizes, int n_in,
                              void* d_out, int out_size, void* d_ws, size_t ws_size,
                              hipStream_t stream) {
    const float* x       = (const float*)d_in[0];
    const int*   adj     = (const int*)d_in[1];
    const float* Wp      = (const float*)d_in[2];
    const float* bp      = (const float*)d_in[3];
    const float* Wg      = (const float*)d_in[4];
    const float* att_src = (const float*)d_in[5];
    const float* att_dst = (const float*)d_in[6];
    const float* bias_g  = (const float*)d_in[7];
    const float* W1      = (const float*)d_in[8];
    const float* b1      = (const float*)d_in[9];
    const float* w2      = (const float*)d_in[10];
    const float* b2      = (const float*)d_in[11];
    float* out = (float*)d_out;
    float* ws = (float*)d_ws;

    // zero the atomic accumulators (lsum + acc contiguous)
    hipMemsetAsync(ws + OFF_LSUM, 0, (32768u + 262144u) * sizeof(float), stream);

    k0_node<<<dim3(32), dim3(256), 0, stream>>>(x, Wp, bp, Wg, att_src, att_dst, ws);
    k1_aggregate<<<dim3(8, 2, Bq), dim3(256), 0, stream>>>(adj, ws);
    k2_finalize<<<dim3(32), dim3(256), 0, stream>>>(bias_g, W1, b1, ws);
    k3_score<<<dim3(32, Bq), dim3(512), 0, stream>>>(w2, b2, ws, out);
}

// Round 2
// 205.477 us; speedup vs baseline: 1.0732x; 1.0732x over previous
//
#include <hip/hip_runtime.h>
#include <cstdint>

#define Bq 16
#define Nq 512
#define Dq 12
#define HID 32
#define HEADS 4
#define Cq 8

// ws layout (float offsets)
#define OFF_G     0u        // [b][n][32]         262144 floats
#define OFF_AS    262144u   // [b][n][4]           32768
#define OFF_AD    294912u   // [b][n][4]           32768
#define OFF_LSUM  327680u   // [b][h][j]           32768  (atomic, zeroed)
#define OFF_ACC   360448u   // [b][h][c][j]       262144  (atomic, zeroed)
#define OFF_TI    622592u   // [b][n][32]         262144
#define OFF_TJB   884736u   // [b][h][j]          262144
#define OFF_PACK  1146880u  // uint64 [b][i][j/64] 65536 u64 (as float offset)

__global__ void k0_node(const float* __restrict__ x, const float* __restrict__ Wp,
                        const float* __restrict__ bp, const float* __restrict__ Wg,
                        const float* __restrict__ att_src, const float* __restrict__ att_dst,
                        float* __restrict__ ws) {
    int nid = blockIdx.x * blockDim.x + threadIdx.x;
    if (nid >= Bq * Nq) return;
    float xv[Dq];
#pragma unroll
    for (int d = 0; d < Dq; d++) xv[d] = x[nid * Dq + d];
    float h[HID];
#pragma unroll
    for (int k = 0; k < HID; k++) {
        float s = bp[k];
#pragma unroll
        for (int d = 0; d < Dq; d++) s = fmaf(Wp[k * Dq + d], xv[d], s);
        h[k] = s > 0.f ? s : 0.f;
    }
    float g[HID];
#pragma unroll
    for (int k = 0; k < HID; k++) {
        float s = 0.f;
#pragma unroll
        for (int d = 0; d < HID; d++) s = fmaf(Wg[k * HID + d], h[d], s);
        g[k] = s;
    }
    float* gout = ws + OFF_G + (size_t)nid * HID;
#pragma unroll
    for (int k = 0; k < HID; k++) gout[k] = g[k];
#pragma unroll
    for (int hh = 0; hh < HEADS; hh++) {
        float ss = 0.f, sd = 0.f;
#pragma unroll
        for (int c = 0; c < Cq; c++) {
            ss = fmaf(g[hh * Cq + c], att_src[hh * Cq + c], ss);
            sd = fmaf(g[hh * Cq + c], att_dst[hh * Cq + c], sd);
        }
        ws[OFF_AS + nid * HEADS + hh] = ss;
        ws[OFF_AD + nid * HEADS + hh] = sd;
    }
}

// grid (ichunk=32, jtile=2, b=16) = 1024 blocks, block 256. Thread owns j, 16 i's.
// g/a_s for the chunk staged in LDS; adj prefetched to registers.
__global__ void __launch_bounds__(256) k1_aggregate(const int* __restrict__ adj,
                                                    float* __restrict__ ws) {
    int b = blockIdx.z;
    int j = blockIdx.y * 256 + threadIdx.x;
    int i0 = blockIdx.x * 16;
    __shared__ float gs[16 * HID];    // 2 KB
    __shared__ float ass[16 * HEADS]; // 256 B
    {
        const float* gsrc = ws + OFF_G + ((size_t)b * Nq + i0) * HID;
        for (int t = threadIdx.x; t < 16 * HID; t += 256) gs[t] = gsrc[t];
        const float* asrc = ws + OFF_AS + ((size_t)b * Nq + i0) * HEADS;
        if (threadIdx.x < 16 * HEADS) ass[threadIdx.x] = asrc[threadIdx.x];
    }
    float adv[HEADS];
#pragma unroll
    for (int h = 0; h < HEADS; h++) adv[h] = ws[OFF_AD + ((size_t)b * Nq + j) * HEADS + h];

    // prefetch adj column slice: 16 independent coalesced loads
    int avv[16];
#pragma unroll
    for (int ii = 0; ii < 16; ii++)
        avv[ii] = adj[((size_t)b * Nq + (i0 + ii)) * Nq + j];

    __syncthreads();

    uint64_t* packed = (uint64_t*)(ws + OFF_PACK);
    float lsum[HEADS] = {0.f, 0.f, 0.f, 0.f};
    float acc[HEADS][Cq] = {};

#pragma unroll
    for (int ii = 0; ii < 16; ii++) {
        int i = i0 + ii;
        unsigned long long m = __ballot(avv[ii] != 0);
        if ((threadIdx.x & 63) == 0)
            packed[((size_t)b * Nq + i) * (Nq / 64) + (j >> 6)] = m;
        bool msk = (avv[ii] != 0) || (i == j);
#pragma unroll
        for (int h = 0; h < HEADS; h++) {
            float z = ass[ii * HEADS + h] + adv[h];
            float lk = z > 0.f ? z : 0.2f * z;
            float e = msk ? __expf(lk) : 0.f;   // no max-shift: |z| small, exact enough
            lsum[h] += e;
#pragma unroll
            for (int c = 0; c < Cq; c++)
                acc[h][c] = fmaf(e, gs[ii * HID + h * Cq + c], acc[h][c]);
        }
    }
    float* lsw = ws + OFF_LSUM;
    float* accw = ws + OFF_ACC;
#pragma unroll
    for (int h = 0; h < HEADS; h++) {
        atomicAdd(&lsw[(b * HEADS + h) * Nq + j], lsum[h]);
#pragma unroll
        for (int c = 0; c < Cq; c++)
            atomicAdd(&accw[((b * HEADS + h) * Cq + c) * Nq + j], acc[h][c]);
    }
}

__global__ void k2_finalize(const float* __restrict__ bias_g, const float* __restrict__ W1,
                            const float* __restrict__ b1, float* __restrict__ ws) {
    int nid = blockIdx.x * blockDim.x + threadIdx.x;
    if (nid >= Bq * Nq) return;
    int b = nid >> 9, j = nid & (Nq - 1);
    float hg[HID];
#pragma unroll
    for (int h = 0; h < HEADS; h++) {
        float inv = 1.f / ws[OFF_LSUM + (b * HEADS + h) * Nq + j];
#pragma unroll
        for (int c = 0; c < Cq; c++)
            hg[h * Cq + c] = ws[OFF_ACC + ((b * HEADS + h) * Cq + c) * Nq + j] * inv
                             + bias_g[h * Cq + c];
    }
#pragma unroll
    for (int h = 0; h < HID; h++) {
        float si = 0.f, sj = 0.f;
#pragma unroll
        for (int d = 0; d < HID; d++) {
            si = fmaf(hg[d], W1[h * 2 * HID + d], si);
            sj = fmaf(hg[d], W1[h * 2 * HID + HID + d], sj);
        }
        ws[OFF_TI + (size_t)nid * HID + h] = si;
        ws[OFF_TJB + (b * HID + h) * Nq + j] = sj + b1[h];  // fold b1 here
    }
}

// grid (N/16=32 i-tiles, b=16), block 512: thread owns j; ti tile staged in LDS.
__global__ void __launch_bounds__(512) k3_score(const float* __restrict__ w2_p,
                                                const float* __restrict__ b2_p,
                                                const float* __restrict__ ws,
                                                float* __restrict__ out) {
    int b = blockIdx.y;
    int i0 = blockIdx.x * 16;
    int j = threadIdx.x;
    __shared__ float tis[16 * HID];   // 2 KB — exactly 512 floats
    tis[threadIdx.x] = ws[OFF_TI + ((size_t)b * Nq + i0) * HID + threadIdx.x];

    float tjb[HID];
#pragma unroll
    for (int h = 0; h < HID; h++) tjb[h] = ws[OFF_TJB + (b * HID + h) * Nq + j];
    float w2l[HID];
#pragma unroll
    for (int h = 0; h < HID; h++) w2l[h] = w2_p[h];
    float b2 = b2_p[0];
    __syncthreads();

    const uint64_t* packed = (const uint64_t*)(ws + OFF_PACK);
    for (int ii = 0; ii < 16; ii++) {
        int i = i0 + ii;
        uint64_t m = packed[((size_t)b * Nq + i) * (Nq / 64) + (j >> 6)];
        bool on = (((m >> (j & 63)) & 1ull) != 0) && (i != j);
        float s = b2;
#pragma unroll
        for (int h = 0; h < HID; h++) {
            float t = tis[ii * HID + h] + tjb[h];
            t = t > 0.f ? t : 0.f;
            s = fmaf(t, w2l[h], s);
        }
        float score = 1.f / (1.f + __expf(-s));
        out[((size_t)b * Nq + i) * Nq + j] = on ? score : 0.f;
    }
}

extern "C" void kernel_launch(void* const* d_in, const int* in_sizes, int n_in,
                              void* d_out, int out_size, void* d_ws, size_t ws_size,
                              hipStream_t stream) {
    const float* x       = (const float*)d_in[0];
    const int*   adj     = (const int*)d_in[1];
    const float* Wp      = (const float*)d_in[2];
    const float* bp      = (const float*)d_in[3];
    const float* Wg      = (const float*)d_in[4];
    const float* att_src = (const float*)d_in[5];
    const float* att_dst = (const float*)d_in[6];
    const float* bias_g  = (const float*)d_in[7];
    const float* W1      = (const float*)d_in[8];
    const float* b1      = (const float*)d_in[9];
    const float* w2      = (const float*)d_in[10];
    const float* b2      = (const float*)d_in[11];
    float* out = (float*)d_out;
    float* ws = (float*)d_ws;

    // zero the atomic accumulators (lsum + acc contiguous)
    hipMemsetAsync(ws + OFF_LSUM, 0, (32768u + 262144u) * sizeof(float), stream);

    k0_node<<<dim3(32), dim3(256), 0, stream>>>(x, Wp, bp, Wg, att_src, att_dst, ws);
    k1_aggregate<<<dim3(32, 2, Bq), dim3(256), 0, stream>>>(adj, ws);
    k2_finalize<<<dim3(32), dim3(256), 0, stream>>>(bias_g, W1, b1, ws);
    k3_score<<<dim3(32, Bq), dim3(512), 0, stream>>>(w2, b2, ws, out);
}